// Round 1
// baseline (6591.072 us; speedup 1.0000x reference)
//
#include <hip/hip_runtime.h>

#define INDIM 64
#define HID   128
#define NCLS  50

// ---------------------------------------------------------------------------
// encoder: feat = relu(x @ W_in + b_in)   [N,64] @ [64,128]
// block 256, tile = 64 rows x 128 cols, W_in (32KB) staged in LDS
// ---------------------------------------------------------------------------
__global__ __launch_bounds__(256) void k_encoder(
    const float* __restrict__ x, const float* __restrict__ W,
    const float* __restrict__ b, float* __restrict__ feat, int N)
{
  __shared__ float Ws[INDIM][HID];   // 32 KB
  __shared__ float bs[HID];
  __shared__ float xs[64][INDIM];    // 16 KB

  for (int i = threadIdx.x; i < INDIM * HID / 4; i += 256)
    reinterpret_cast<float4*>(Ws)[i] = reinterpret_cast<const float4*>(W)[i];
  if (threadIdx.x < HID) bs[threadIdx.x] = b[threadIdx.x];

  const int c4 = (threadIdx.x & 31) * 4;
  const int rg = threadIdx.x >> 5;   // 0..7, 8 rows each

  for (int rb = blockIdx.x * 64; rb < N; rb += gridDim.x * 64) {
    __syncthreads();   // protects xs reuse; also orders Ws/bs staging on iter 0
    #pragma unroll
    for (int j = 0; j < 4; j++) {
      int i = threadIdx.x + j * 256;
      int r = i >> 4, k4 = (i & 15) * 4;
      int row = rb + r;
      float4 v = make_float4(0.f, 0.f, 0.f, 0.f);
      if (row < N) v = *reinterpret_cast<const float4*>(&x[row * INDIM + k4]);
      *reinterpret_cast<float4*>(&xs[r][k4]) = v;
    }
    __syncthreads();

    float4 acc[8];
    float4 bv = *reinterpret_cast<float4*>(&bs[c4]);
    #pragma unroll
    for (int rr = 0; rr < 8; rr++) acc[rr] = bv;

    #pragma unroll
    for (int k = 0; k < INDIM; k++) {
      float4 wv = *reinterpret_cast<float4*>(&Ws[k][c4]);
      #pragma unroll
      for (int rr = 0; rr < 8; rr++) {
        float a = xs[rg * 8 + rr][k];
        acc[rr].x += a * wv.x; acc[rr].y += a * wv.y;
        acc[rr].z += a * wv.z; acc[rr].w += a * wv.w;
      }
    }
    #pragma unroll
    for (int rr = 0; rr < 8; rr++) {
      int row = rb + rg * 8 + rr;
      if (row < N) {
        float4 o;
        o.x = fmaxf(acc[rr].x, 0.f); o.y = fmaxf(acc[rr].y, 0.f);
        o.z = fmaxf(acc[rr].z, 0.f); o.w = fmaxf(acc[rr].w, 0.f);
        *reinterpret_cast<float4*>(&feat[row * HID + c4]) = o;
      }
    }
  }
}

// ---------------------------------------------------------------------------
// CSR build: count -> single-block scan -> fill
// ---------------------------------------------------------------------------
__global__ void k_count(const int* __restrict__ dst, int* __restrict__ cnt, int E)
{
  int i = blockIdx.x * 256 + threadIdx.x;
  if (i < E) atomicAdd(&cnt[dst[i]], 1);
}

__global__ __launch_bounds__(1024) void k_scan(
    const int* __restrict__ cnt, int* __restrict__ rs, int* __restrict__ cur,
    int N, int E)
{
  __shared__ int part[1024];
  const int t = threadIdx.x;
  const int chunk = (N + 1023) / 1024;
  const int b0 = t * chunk;
  const int b1 = min(b0 + chunk, N);
  int s = 0;
  for (int i = b0; i < b1; i++) s += cnt[i];
  part[t] = s;
  __syncthreads();
  for (int off = 1; off < 1024; off <<= 1) {
    int v = (t >= off) ? part[t - off] : 0;
    __syncthreads();
    part[t] += v;
    __syncthreads();
  }
  int base = part[t] - s;  // exclusive prefix
  for (int i = b0; i < b1; i++) {
    rs[i] = base; cur[i] = base;
    base += cnt[i];
  }
  if (t == 0) rs[N] = E;
}

__global__ void k_fill(const int* __restrict__ src, const int* __restrict__ dst,
                       int* __restrict__ cur, int* __restrict__ csr, int E)
{
  int i = blockIdx.x * 256 + threadIdx.x;
  if (i < E) {
    int d = dst[i];
    int pos = atomicAdd(&cur[d], 1);
    csr[pos] = src[i];
  }
}

// ---------------------------------------------------------------------------
// mean aggregation: one wave per dst row, float2 per lane (64 lanes * 8B = row)
// ---------------------------------------------------------------------------
__global__ __launch_bounds__(256) void k_agg(
    const float* __restrict__ feat, const int* __restrict__ rs,
    const int* __restrict__ csr, float* __restrict__ mean, int N)
{
  const int lane = threadIdx.x & 63;
  const int gw = (blockIdx.x * 256 + threadIdx.x) >> 6;
  const int nw = (gridDim.x * 256) >> 6;
  for (int r = gw; r < N; r += nw) {
    int s0 = rs[r], s1 = rs[r + 1];
    float ax = 0.f, ay = 0.f;
    for (int e = s0; e < s1; e++) {
      int sidx = csr[e];
      float2 v = *reinterpret_cast<const float2*>(&feat[sidx * HID + lane * 2]);
      ax += v.x; ay += v.y;
    }
    float inv = 1.f / (float)max(s1 - s0, 1);
    float2 m = make_float2(ax * inv, ay * inv);
    *reinterpret_cast<float2*>(&mean[r * HID + lane * 2]) = m;
  }
}

// ---------------------------------------------------------------------------
// combine: out_feat = mean @ W_l + b_l + feat @ W_r   (K = 2x128 in 4 chunks)
// block 256, tile 64 rows x 128 cols; A-chunk 16KB + B-chunk 32KB in LDS
// NOTE: feat aliases the out_feat output region — safe: each block reads only
// its own rows (all 4 chunks) before writing those same rows.
// ---------------------------------------------------------------------------
__global__ __launch_bounds__(256) void k_combine(
    const float* __restrict__ mean, const float* __restrict__ feat,
    const float* __restrict__ Wl, const float* __restrict__ Wr,
    const float* __restrict__ bl, float* __restrict__ outf, int N)
{
  __shared__ float As[64][INDIM];   // 16 KB (64 rows x 64-k chunk)
  __shared__ float Bs[64][HID];     // 32 KB
  __shared__ float bls[HID];
  if (threadIdx.x < HID) bls[threadIdx.x] = bl[threadIdx.x];

  const int c4 = (threadIdx.x & 31) * 4;
  const int rg = threadIdx.x >> 5;

  for (int rb = blockIdx.x * 64; rb < N; rb += gridDim.x * 64) {
    float4 acc[8];
    #pragma unroll
    for (int ch = 0; ch < 4; ch++) {
      const float* Asrc = (ch < 2) ? mean : feat;
      const float* Wsrc = (ch < 2) ? Wl : Wr;
      const int k0 = (ch & 1) * 64;

      __syncthreads();   // protect As/Bs reuse (and bls on first pass)
      #pragma unroll
      for (int j = 0; j < 4; j++) {
        int i = threadIdx.x + j * 256;
        int r = i >> 4, k4 = (i & 15) * 4;
        int row = rb + r;
        float4 v = make_float4(0.f, 0.f, 0.f, 0.f);
        if (row < N) v = *reinterpret_cast<const float4*>(&Asrc[row * HID + k0 + k4]);
        *reinterpret_cast<float4*>(&As[r][k4]) = v;
      }
      #pragma unroll
      for (int j = 0; j < 8; j++) {
        int i = threadIdx.x + j * 256;
        int k = i >> 5, cc4 = (i & 31) * 4;
        *reinterpret_cast<float4*>(&Bs[k][cc4]) =
            *reinterpret_cast<const float4*>(&Wsrc[(k0 + k) * HID + cc4]);
      }
      __syncthreads();

      if (ch == 0) {
        float4 bv = *reinterpret_cast<float4*>(&bls[c4]);
        #pragma unroll
        for (int rr = 0; rr < 8; rr++) acc[rr] = bv;
      }
      #pragma unroll
      for (int k = 0; k < 64; k++) {
        float4 bv = *reinterpret_cast<float4*>(&Bs[k][c4]);
        #pragma unroll
        for (int rr = 0; rr < 8; rr++) {
          float a = As[rg * 8 + rr][k];
          acc[rr].x += a * bv.x; acc[rr].y += a * bv.y;
          acc[rr].z += a * bv.z; acc[rr].w += a * bv.w;
        }
      }
    }
    #pragma unroll
    for (int rr = 0; rr < 8; rr++) {
      int row = rb + rg * 8 + rr;
      if (row < N)
        *reinterpret_cast<float4*>(&outf[row * HID + c4]) = acc[rr];
    }
  }
}

// ---------------------------------------------------------------------------
// classifier head
// ---------------------------------------------------------------------------
__global__ void k_wn(const float* __restrict__ Wc, float* __restrict__ wn)
{
  int c = threadIdx.x;
  if (c >= NCLS) return;
  float s = 0.f;
  for (int k = 0; k < HID; k++) { float v = Wc[k * NCLS + c]; s += v * v; }
  float scale = 1.f / fmaxf(sqrtf(s), 1e-12f);
  for (int k = 0; k < HID; k++) wn[k * NCLS + c] = Wc[k * NCLS + c] * scale;
}

// one wave per row: lanes hold dims, row-normalize, then lane=class via shfl
__global__ __launch_bounds__(256) void k_classifier(
    const float* __restrict__ outf, const float* __restrict__ wn,
    float* __restrict__ out, int N)
{
  __shared__ float wns[HID * NCLS + 64];   // padded: lanes 50..63 read garbage, never stored
  for (int i = threadIdx.x; i < HID * NCLS / 2; i += 256)
    reinterpret_cast<float2*>(wns)[i] = reinterpret_cast<const float2*>(wn)[i];
  __syncthreads();

  const int lane = threadIdx.x & 63;
  const int gw = (blockIdx.x * 256 + threadIdx.x) >> 6;
  const int nw = (gridDim.x * 256) >> 6;

  for (int r = gw; r < N; r += nw) {
    float of0 = outf[r * HID + lane];
    float of1 = outf[r * HID + 64 + lane];
    float ss = of0 * of0 + of1 * of1;
    #pragma unroll
    for (int off = 32; off >= 1; off >>= 1) ss += __shfl_xor(ss, off);
    float scale = 10.f / fmaxf(sqrtf(ss), 1e-12f);

    float acc = 0.f;
    #pragma unroll
    for (int k = 0; k < 64; k++) {
      float a0 = __shfl(of0, k);
      float a1 = __shfl(of1, k);
      acc += a0 * wns[k * NCLS + lane];
      acc += a1 * wns[(k + 64) * NCLS + lane];
    }
    if (lane < NCLS) out[r * NCLS + lane] = scale * acc;
  }
}

// ---------------------------------------------------------------------------
extern "C" void kernel_launch(void* const* d_in, const int* in_sizes, int n_in,
                              void* d_out, int out_size, void* d_ws, size_t ws_size,
                              hipStream_t stream)
{
  const float* x     = (const float*)d_in[0];
  const int*   ei    = (const int*)d_in[1];
  const float* W_in  = (const float*)d_in[2];
  const float* b_in  = (const float*)d_in[3];
  const float* W_l   = (const float*)d_in[4];
  const float* b_l   = (const float*)d_in[5];
  const float* W_r   = (const float*)d_in[6];
  const float* W_cls = (const float*)d_in[7];

  const int N = in_sizes[0] / INDIM;
  const int E = in_sizes[1] / 2;
  const int* src = ei;
  const int* dst = ei + E;

  float* out  = (float*)d_out;
  float* outf = out + (size_t)N * NCLS;   // out_feat output region
  float* feat = outf;                     // encoder output aliases out_feat (see k_combine note)

  char* ws = (char*)d_ws;
  size_t off = 0;
  auto alloc = [&](size_t bytes) -> void* {
    void* p = ws + off;
    off = (off + bytes + 255) & ~(size_t)255;
    return p;
  };
  float* mean = (float*)alloc((size_t)N * HID * 4);
  float* wn   = (float*)alloc((size_t)HID * NCLS * 4);
  int*   cnt  = (int*)alloc((size_t)N * 4);
  int*   rs   = (int*)alloc((size_t)(N + 1) * 4);
  int*   cur  = (int*)alloc((size_t)N * 4);
  int*   csr  = (int*)alloc((size_t)E * 4);
  (void)ws_size; (void)n_in; (void)out_size;

  hipMemsetAsync(cnt, 0, (size_t)N * 4, stream);
  k_wn<<<1, 64, 0, stream>>>(W_cls, wn);
  k_encoder<<<(N + 63) / 64, 256, 0, stream>>>(x, W_in, b_in, feat, N);
  k_count<<<(E + 255) / 256, 256, 0, stream>>>(dst, cnt, E);
  k_scan<<<1, 1024, 0, stream>>>(cnt, rs, cur, N, E);
  k_fill<<<(E + 255) / 256, 256, 0, stream>>>(src, dst, cur, csr, E);
  k_agg<<<4096, 256, 0, stream>>>(feat, rs, csr, mean, N);
  k_combine<<<(N + 63) / 64, 256, 0, stream>>>(mean, feat, W_l, W_r, b_l, outf, N);
  k_classifier<<<2048, 256, 0, stream>>>(outf, wn, out, N);
}

// Round 5
// 964.437 us; speedup vs baseline: 6.8341x; 6.8341x over previous
//
#include <hip/hip_runtime.h>

#define INDIM 64
#define HID   128
#define NCLS  50

// ---------------------------------------------------------------------------
// encoder: feat = relu(x @ W_in + b_in)   [N,64] @ [64,128]
// block 256, tile = 64 rows x 128 cols, W_in (32KB) staged in LDS
// ---------------------------------------------------------------------------
__global__ __launch_bounds__(256) void k_encoder(
    const float* __restrict__ x, const float* __restrict__ W,
    const float* __restrict__ b, float* __restrict__ feat, int N)
{
  __shared__ float Ws[INDIM][HID];   // 32 KB
  __shared__ float bs[HID];
  __shared__ float xs[64][INDIM];    // 16 KB

  for (int i = threadIdx.x; i < INDIM * HID / 4; i += 256)
    reinterpret_cast<float4*>(Ws)[i] = reinterpret_cast<const float4*>(W)[i];
  if (threadIdx.x < HID) bs[threadIdx.x] = b[threadIdx.x];

  const int c4 = (threadIdx.x & 31) * 4;
  const int rg = threadIdx.x >> 5;   // 0..7, 8 rows each

  for (int rb = blockIdx.x * 64; rb < N; rb += gridDim.x * 64) {
    __syncthreads();   // protects xs reuse; also orders Ws/bs staging on iter 0
    #pragma unroll
    for (int j = 0; j < 4; j++) {
      int i = threadIdx.x + j * 256;
      int r = i >> 4, k4 = (i & 15) * 4;
      int row = rb + r;
      float4 v = make_float4(0.f, 0.f, 0.f, 0.f);
      if (row < N) v = *reinterpret_cast<const float4*>(&x[row * INDIM + k4]);
      *reinterpret_cast<float4*>(&xs[r][k4]) = v;
    }
    __syncthreads();

    float4 acc[8];
    float4 bv = *reinterpret_cast<float4*>(&bs[c4]);
    #pragma unroll
    for (int rr = 0; rr < 8; rr++) acc[rr] = bv;

    // capped unroll: keep the body well under the 32 KB I-cache
    #pragma unroll 8
    for (int k = 0; k < INDIM; k++) {
      float4 wv = *reinterpret_cast<float4*>(&Ws[k][c4]);
      #pragma unroll
      for (int rr = 0; rr < 8; rr++) {
        float a = xs[rg * 8 + rr][k];
        acc[rr].x += a * wv.x; acc[rr].y += a * wv.y;
        acc[rr].z += a * wv.z; acc[rr].w += a * wv.w;
      }
    }
    #pragma unroll
    for (int rr = 0; rr < 8; rr++) {
      int row = rb + rg * 8 + rr;
      if (row < N) {
        float4 o;
        o.x = fmaxf(acc[rr].x, 0.f); o.y = fmaxf(acc[rr].y, 0.f);
        o.z = fmaxf(acc[rr].z, 0.f); o.w = fmaxf(acc[rr].w, 0.f);
        *reinterpret_cast<float4*>(&feat[row * HID + c4]) = o;
      }
    }
  }
}

// ---------------------------------------------------------------------------
// CSR build: count -> single-block scan -> fill
// ---------------------------------------------------------------------------
__global__ void k_count(const int* __restrict__ dst, int* __restrict__ cnt, int E)
{
  int i = blockIdx.x * 256 + threadIdx.x;
  if (i < E) atomicAdd(&cnt[dst[i]], 1);
}

__global__ __launch_bounds__(1024) void k_scan(
    const int* __restrict__ cnt, int* __restrict__ rs, int* __restrict__ cur,
    int N, int E)
{
  __shared__ int part[1024];
  const int t = threadIdx.x;
  const int chunk = (N + 1023) / 1024;
  const int b0 = t * chunk;
  const int b1 = min(b0 + chunk, N);
  int s = 0;
  for (int i = b0; i < b1; i++) s += cnt[i];
  part[t] = s;
  __syncthreads();
  for (int off = 1; off < 1024; off <<= 1) {
    int v = (t >= off) ? part[t - off] : 0;
    __syncthreads();
    part[t] += v;
    __syncthreads();
  }
  int base = part[t] - s;  // exclusive prefix
  for (int i = b0; i < b1; i++) {
    rs[i] = base; cur[i] = base;
    base += cnt[i];
  }
  if (t == 0) rs[N] = E;
}

__global__ void k_fill(const int* __restrict__ src, const int* __restrict__ dst,
                       int* __restrict__ cur, int* __restrict__ csr, int E)
{
  int i = blockIdx.x * 256 + threadIdx.x;
  if (i < E) {
    int d = dst[i];
    int pos = atomicAdd(&cur[d], 1);
    csr[pos] = src[i];
  }
}

// ---------------------------------------------------------------------------
// mean aggregation: one wave per dst row, float2 per lane (64 lanes * 8B = row)
// 2-deep manual pipeline to break the csr->feat dependent-load chain
// ---------------------------------------------------------------------------
__global__ __launch_bounds__(256) void k_agg(
    const float* __restrict__ feat, const int* __restrict__ rs,
    const int* __restrict__ csr, float* __restrict__ mean, int N)
{
  const int lane = threadIdx.x & 63;
  const int gw = (blockIdx.x * 256 + threadIdx.x) >> 6;
  const int nw = (gridDim.x * 256) >> 6;
  for (int r = gw; r < N; r += nw) {
    int s0 = rs[r], s1 = rs[r + 1];
    float ax = 0.f, ay = 0.f, bx = 0.f, by = 0.f;
    int e = s0;
    for (; e + 1 < s1; e += 2) {
      int i0 = csr[e];
      int i1 = csr[e + 1];
      float2 v0 = *reinterpret_cast<const float2*>(&feat[(size_t)i0 * HID + lane * 2]);
      float2 v1 = *reinterpret_cast<const float2*>(&feat[(size_t)i1 * HID + lane * 2]);
      ax += v0.x; ay += v0.y;
      bx += v1.x; by += v1.y;
    }
    if (e < s1) {
      int i0 = csr[e];
      float2 v0 = *reinterpret_cast<const float2*>(&feat[(size_t)i0 * HID + lane * 2]);
      ax += v0.x; ay += v0.y;
    }
    ax += bx; ay += by;
    float inv = 1.f / (float)max(s1 - s0, 1);
    float2 m = make_float2(ax * inv, ay * inv);
    *reinterpret_cast<float2*>(&mean[r * HID + lane * 2]) = m;
  }
}

// ---------------------------------------------------------------------------
// combine: out_feat = mean @ W_l + b_l + feat @ W_r   (K = 2x128 in 4 chunks)
// block 256, tile 64 rows x 128 cols; A-chunk 16KB + B-chunk 32KB in LDS.
// ch loop is NOT unrolled and k loop is capped at 8: the round-1 version fully
// unrolled everything (~84KB body) and thrashed the 32KB I-cache (VALUBusy 1%).
// NOTE: feat aliases the out_feat output region (no __restrict__ on them) —
// safe: each block reads only its own rows (all chunks) before writing them.
// ---------------------------------------------------------------------------
__global__ __launch_bounds__(256) void k_combine(
    const float* __restrict__ mean, const float* feat,
    const float* __restrict__ Wl, const float* __restrict__ Wr,
    const float* __restrict__ bl, float* outf, int N)
{
  __shared__ float As[64][INDIM];   // 16 KB (64 rows x 64-k chunk)
  __shared__ float Bs[64][HID];     // 32 KB
  __shared__ float bls[HID];
  if (threadIdx.x < HID) bls[threadIdx.x] = bl[threadIdx.x];

  const int c4 = (threadIdx.x & 31) * 4;
  const int rg = threadIdx.x >> 5;

  for (int rb = blockIdx.x * 64; rb < N; rb += gridDim.x * 64) {
    float4 acc[8];
    #pragma unroll 1
    for (int ch = 0; ch < 4; ch++) {
      const float* Asrc = (ch < 2) ? mean : feat;
      const float* Wsrc = (ch < 2) ? Wl : Wr;
      const int k0 = (ch & 1) * 64;

      __syncthreads();   // protect As/Bs reuse (and bls on first pass)
      #pragma unroll
      for (int j = 0; j < 4; j++) {
        int i = threadIdx.x + j * 256;
        int r = i >> 4, k4 = (i & 15) * 4;
        int row = rb + r;
        float4 v = make_float4(0.f, 0.f, 0.f, 0.f);
        if (row < N) v = *reinterpret_cast<const float4*>(&Asrc[row * HID + k0 + k4]);
        *reinterpret_cast<float4*>(&As[r][k4]) = v;
      }
      #pragma unroll
      for (int j = 0; j < 8; j++) {
        int i = threadIdx.x + j * 256;
        int k = i >> 5, cc4 = (i & 31) * 4;
        *reinterpret_cast<float4*>(&Bs[k][cc4]) =
            *reinterpret_cast<const float4*>(&Wsrc[(k0 + k) * HID + cc4]);
      }
      __syncthreads();

      if (ch == 0) {
        float4 bv = *reinterpret_cast<float4*>(&bls[c4]);
        #pragma unroll
        for (int rr = 0; rr < 8; rr++) acc[rr] = bv;
      }
      #pragma unroll 8
      for (int k = 0; k < 64; k++) {
        float4 bv = *reinterpret_cast<float4*>(&Bs[k][c4]);
        #pragma unroll
        for (int rr = 0; rr < 8; rr++) {
          float a = As[rg * 8 + rr][k];
          acc[rr].x += a * bv.x; acc[rr].y += a * bv.y;
          acc[rr].z += a * bv.z; acc[rr].w += a * bv.w;
        }
      }
    }
    #pragma unroll
    for (int rr = 0; rr < 8; rr++) {
      int row = rb + rg * 8 + rr;
      if (row < N)
        *reinterpret_cast<float4*>(&outf[row * HID + c4]) = acc[rr];
    }
  }
}

// ---------------------------------------------------------------------------
// classifier head
// ---------------------------------------------------------------------------
__global__ void k_wn(const float* __restrict__ Wc, float* __restrict__ wn)
{
  int c = threadIdx.x;
  if (c >= NCLS) return;
  float s = 0.f;
  for (int k = 0; k < HID; k++) { float v = Wc[k * NCLS + c]; s += v * v; }
  float scale = 1.f / fmaxf(sqrtf(s), 1e-12f);
  for (int k = 0; k < HID; k++) wn[k * NCLS + c] = Wc[k * NCLS + c] * scale;
}

// one wave per row: lanes hold dims, row-normalize, then lane=class via shfl
__global__ __launch_bounds__(256) void k_classifier(
    const float* __restrict__ outf, const float* __restrict__ wn,
    float* __restrict__ out, int N)
{
  __shared__ float wns[HID * NCLS + 64];   // padded: lanes 50..63 read garbage, never stored
  for (int i = threadIdx.x; i < HID * NCLS / 2; i += 256)
    reinterpret_cast<float2*>(wns)[i] = reinterpret_cast<const float2*>(wn)[i];
  __syncthreads();

  const int lane = threadIdx.x & 63;
  const int gw = (blockIdx.x * 256 + threadIdx.x) >> 6;
  const int nw = (gridDim.x * 256) >> 6;

  for (int r = gw; r < N; r += nw) {
    float of0 = outf[r * HID + lane];
    float of1 = outf[r * HID + 64 + lane];
    float ss = of0 * of0 + of1 * of1;
    #pragma unroll
    for (int off = 32; off >= 1; off >>= 1) ss += __shfl_xor(ss, off);
    float scale = 10.f / fmaxf(sqrtf(ss), 1e-12f);

    float acc = 0.f;
    #pragma unroll 4
    for (int k = 0; k < 64; k++) {
      float a0 = __shfl(of0, k);
      float a1 = __shfl(of1, k);
      acc += a0 * wns[k * NCLS + lane];
      acc += a1 * wns[(k + 64) * NCLS + lane];
    }
    if (lane < NCLS) out[r * NCLS + lane] = scale * acc;
  }
}

// ---------------------------------------------------------------------------
extern "C" void kernel_launch(void* const* d_in, const int* in_sizes, int n_in,
                              void* d_out, int out_size, void* d_ws, size_t ws_size,
                              hipStream_t stream)
{
  const float* x     = (const float*)d_in[0];
  const int*   ei    = (const int*)d_in[1];
  const float* W_in  = (const float*)d_in[2];
  const float* b_in  = (const float*)d_in[3];
  const float* W_l   = (const float*)d_in[4];
  const float* b_l   = (const float*)d_in[5];
  const float* W_r   = (const float*)d_in[6];
  const float* W_cls = (const float*)d_in[7];

  const int N = in_sizes[0] / INDIM;
  const int E = in_sizes[1] / 2;
  const int* src = ei;
  const int* dst = ei + E;

  float* out  = (float*)d_out;
  float* outf = out + (size_t)N * NCLS;   // out_feat output region
  float* feat = outf;                     // encoder output aliases out_feat (see k_combine note)

  char* ws = (char*)d_ws;
  size_t off = 0;
  auto alloc = [&](size_t bytes) -> void* {
    void* p = ws + off;
    off = (off + bytes + 255) & ~(size_t)255;
    return p;
  };
  float* mean = (float*)alloc((size_t)N * HID * 4);
  float* wn   = (float*)alloc((size_t)HID * NCLS * 4);
  int*   cnt  = (int*)alloc((size_t)N * 4);
  int*   rs   = (int*)alloc((size_t)(N + 1) * 4);
  int*   cur  = (int*)alloc((size_t)N * 4);
  int*   csr  = (int*)alloc((size_t)E * 4);
  (void)ws_size; (void)n_in; (void)out_size;

  hipMemsetAsync(cnt, 0, (size_t)N * 4, stream);
  k_wn<<<1, 64, 0, stream>>>(W_cls, wn);
  k_encoder<<<(N + 63) / 64, 256, 0, stream>>>(x, W_in, b_in, feat, N);
  k_count<<<(E + 255) / 256, 256, 0, stream>>>(dst, cnt, E);
  k_scan<<<1, 1024, 0, stream>>>(cnt, rs, cur, N, E);
  k_fill<<<(E + 255) / 256, 256, 0, stream>>>(src, dst, cur, csr, E);
  k_agg<<<4096, 256, 0, stream>>>(feat, rs, csr, mean, N);
  k_combine<<<(N + 63) / 64, 256, 0, stream>>>(mean, feat, W_l, W_r, b_l, outf, N);
  k_classifier<<<2048, 256, 0, stream>>>(outf, wn, out, N);
}

// Round 8
// 747.565 us; speedup vs baseline: 8.8167x; 1.2901x over previous
//
#include <hip/hip_runtime.h>

#define INDIM 64
#define HID   128
#define NCLS  50
#define SNB   128   // scan blocks
#define SBS   1024  // scan block size

// ---------------------------------------------------------------------------
// encoder: feat = relu(x @ W_in + b_in)   [N,64] @ [64,128]
// block 256, tile = 64 rows x 128 cols, W_in (32KB) staged in LDS
// ---------------------------------------------------------------------------
__global__ __launch_bounds__(256) void k_encoder(
    const float* __restrict__ x, const float* __restrict__ W,
    const float* __restrict__ b, float* __restrict__ feat, int N)
{
  __shared__ float Ws[INDIM][HID];   // 32 KB
  __shared__ float bs[HID];
  __shared__ float xs[64][INDIM];    // 16 KB

  for (int i = threadIdx.x; i < INDIM * HID / 4; i += 256)
    reinterpret_cast<float4*>(Ws)[i] = reinterpret_cast<const float4*>(W)[i];
  if (threadIdx.x < HID) bs[threadIdx.x] = b[threadIdx.x];

  const int c4 = (threadIdx.x & 31) * 4;
  const int rg = threadIdx.x >> 5;   // 0..7, 8 rows each

  for (int rb = blockIdx.x * 64; rb < N; rb += gridDim.x * 64) {
    __syncthreads();   // protects xs reuse; also orders Ws/bs staging on iter 0
    #pragma unroll
    for (int j = 0; j < 4; j++) {
      int i = threadIdx.x + j * 256;
      int r = i >> 4, k4 = (i & 15) * 4;
      int row = rb + r;
      float4 v = make_float4(0.f, 0.f, 0.f, 0.f);
      if (row < N) v = *reinterpret_cast<const float4*>(&x[row * INDIM + k4]);
      *reinterpret_cast<float4*>(&xs[r][k4]) = v;
    }
    __syncthreads();

    float4 acc[8];
    float4 bv = *reinterpret_cast<float4*>(&bs[c4]);
    #pragma unroll
    for (int rr = 0; rr < 8; rr++) acc[rr] = bv;

    // capped unroll: keep the body well under the 32 KB I-cache
    #pragma unroll 8
    for (int k = 0; k < INDIM; k++) {
      float4 wv = *reinterpret_cast<float4*>(&Ws[k][c4]);
      #pragma unroll
      for (int rr = 0; rr < 8; rr++) {
        float a = xs[rg * 8 + rr][k];
        acc[rr].x += a * wv.x; acc[rr].y += a * wv.y;
        acc[rr].z += a * wv.z; acc[rr].w += a * wv.w;
      }
    }
    #pragma unroll
    for (int rr = 0; rr < 8; rr++) {
      int row = rb + rg * 8 + rr;
      if (row < N) {
        float4 o;
        o.x = fmaxf(acc[rr].x, 0.f); o.y = fmaxf(acc[rr].y, 0.f);
        o.z = fmaxf(acc[rr].z, 0.f); o.w = fmaxf(acc[rr].w, 0.f);
        *reinterpret_cast<float4*>(&feat[row * HID + c4]) = o;
      }
    }
  }
}

// ---------------------------------------------------------------------------
// CSR build: count -> hierarchical scan (3 kernels) -> fill
// round-5 profile: the old single-block scan was 230us at 0.15% occupancy
// (1 CU busy, serial per-thread chunk walk). 128-block version parallelizes.
// ---------------------------------------------------------------------------
__global__ void k_count(const int* __restrict__ dst, int* __restrict__ cnt, int E)
{
  int i = blockIdx.x * 256 + threadIdx.x;
  if (i < E) atomicAdd(&cnt[dst[i]], 1);
}

// pass A: per-block chunk totals
__global__ __launch_bounds__(SBS) void k_scan_a(
    const int* __restrict__ cnt, int* __restrict__ part, int N)
{
  __shared__ int red[SBS];
  const int b = blockIdx.x;
  const int chunk = (N + SNB - 1) / SNB;
  const int base = b * chunk;
  const int end = min(base + chunk, N);
  int s = 0;
  for (int i = base + threadIdx.x; i < end; i += SBS) s += cnt[i];
  red[threadIdx.x] = s;
  __syncthreads();
  for (int off = SBS / 2; off >= 1; off >>= 1) {
    if (threadIdx.x < off) red[threadIdx.x] += red[threadIdx.x + off];
    __syncthreads();
  }
  if (threadIdx.x == 0) part[b] = red[0];
}

// pass B: exclusive scan of the SNB partials (single block, 2 waves)
__global__ __launch_bounds__(SNB) void k_scan_b(int* __restrict__ part)
{
  __shared__ int sh[SNB];
  const int t = threadIdx.x;
  const int v = part[t];
  sh[t] = v;
  __syncthreads();
  for (int off = 1; off < SNB; off <<= 1) {
    int u = (t >= off) ? sh[t - off] : 0;
    __syncthreads();
    sh[t] += u;
    __syncthreads();
  }
  part[t] = sh[t] - v;   // exclusive prefix of block totals
}

// pass C: local scan + global offset, write rs/cur
__global__ __launch_bounds__(SBS) void k_scan_c(
    const int* __restrict__ cnt, const int* __restrict__ part,
    int* __restrict__ rs, int* __restrict__ cur, int N, int E)
{
  __shared__ int sh[SBS];
  const int b = blockIdx.x;
  const int chunk = (N + SNB - 1) / SNB;
  const int base = b * chunk;
  const int end = min(base + chunk, N);
  const int len = max(end - base, 0);
  const int sc = (len + SBS - 1) / SBS;       // elems per thread (1 for N=100k)
  const int t0 = base + threadIdx.x * sc;
  const int t1 = min(t0 + sc, end);
  int s = 0;
  for (int i = t0; i < t1; i++) s += cnt[i];
  sh[threadIdx.x] = s;
  __syncthreads();
  for (int off = 1; off < SBS; off <<= 1) {   // inclusive Hillis-Steele
    int u = (threadIdx.x >= off) ? sh[threadIdx.x - off] : 0;
    __syncthreads();
    sh[threadIdx.x] += u;
    __syncthreads();
  }
  int pre = part[b] + sh[threadIdx.x] - s;    // exclusive prefix for this sub-chunk
  for (int i = t0; i < t1; i++) {
    rs[i] = pre; cur[i] = pre;
    pre += cnt[i];
  }
  if (b == 0 && threadIdx.x == 0) rs[N] = E;
}

__global__ void k_fill(const int* __restrict__ src, const int* __restrict__ dst,
                       int* __restrict__ cur, int* __restrict__ csr, int E)
{
  int i = blockIdx.x * 256 + threadIdx.x;
  if (i < E) {
    int d = dst[i];
    int pos = atomicAdd(&cur[d], 1);
    csr[pos] = src[i];
  }
}

// ---------------------------------------------------------------------------
// mean aggregation: one wave per dst row, float2 per lane (64 lanes * 8B = row)
// 2-deep manual pipeline to break the csr->feat dependent-load chain
// ---------------------------------------------------------------------------
__global__ __launch_bounds__(256) void k_agg(
    const float* __restrict__ feat, const int* __restrict__ rs,
    const int* __restrict__ csr, float* __restrict__ mean, int N)
{
  const int lane = threadIdx.x & 63;
  const int gw = (blockIdx.x * 256 + threadIdx.x) >> 6;
  const int nw = (gridDim.x * 256) >> 6;
  for (int r = gw; r < N; r += nw) {
    int s0 = rs[r], s1 = rs[r + 1];
    float ax = 0.f, ay = 0.f, bx = 0.f, by = 0.f;
    int e = s0;
    for (; e + 1 < s1; e += 2) {
      int i0 = csr[e];
      int i1 = csr[e + 1];
      float2 v0 = *reinterpret_cast<const float2*>(&feat[(size_t)i0 * HID + lane * 2]);
      float2 v1 = *reinterpret_cast<const float2*>(&feat[(size_t)i1 * HID + lane * 2]);
      ax += v0.x; ay += v0.y;
      bx += v1.x; by += v1.y;
    }
    if (e < s1) {
      int i0 = csr[e];
      float2 v0 = *reinterpret_cast<const float2*>(&feat[(size_t)i0 * HID + lane * 2]);
      ax += v0.x; ay += v0.y;
    }
    ax += bx; ay += by;
    float inv = 1.f / (float)max(s1 - s0, 1);
    float2 m = make_float2(ax * inv, ay * inv);
    *reinterpret_cast<float2*>(&mean[r * HID + lane * 2]) = m;
  }
}

// ---------------------------------------------------------------------------
// combine: out_feat = mean @ W_l + b_l + feat @ W_r   (K = 2x128 in 4 chunks)
// block 256, tile 64 rows x 128 cols; A-chunk 16KB + B-chunk 32KB in LDS.
// ch loop is NOT unrolled and k loop is capped at 8: the round-1 version fully
// unrolled everything (~84KB body) and thrashed the 32KB I-cache (VALUBusy 1%).
// NOTE: feat aliases the out_feat output region (no __restrict__ on them) —
// safe: each block reads only its own rows (all chunks) before writing them.
// ---------------------------------------------------------------------------
__global__ __launch_bounds__(256) void k_combine(
    const float* __restrict__ mean, const float* feat,
    const float* __restrict__ Wl, const float* __restrict__ Wr,
    const float* __restrict__ bl, float* outf, int N)
{
  __shared__ float As[64][INDIM];   // 16 KB (64 rows x 64-k chunk)
  __shared__ float Bs[64][HID];     // 32 KB
  __shared__ float bls[HID];
  if (threadIdx.x < HID) bls[threadIdx.x] = bl[threadIdx.x];

  const int c4 = (threadIdx.x & 31) * 4;
  const int rg = threadIdx.x >> 5;

  for (int rb = blockIdx.x * 64; rb < N; rb += gridDim.x * 64) {
    float4 acc[8];
    #pragma unroll 1
    for (int ch = 0; ch < 4; ch++) {
      const float* Asrc = (ch < 2) ? mean : feat;
      const float* Wsrc = (ch < 2) ? Wl : Wr;
      const int k0 = (ch & 1) * 64;

      __syncthreads();   // protect As/Bs reuse (and bls on first pass)
      #pragma unroll
      for (int j = 0; j < 4; j++) {
        int i = threadIdx.x + j * 256;
        int r = i >> 4, k4 = (i & 15) * 4;
        int row = rb + r;
        float4 v = make_float4(0.f, 0.f, 0.f, 0.f);
        if (row < N) v = *reinterpret_cast<const float4*>(&Asrc[row * HID + k0 + k4]);
        *reinterpret_cast<float4*>(&As[r][k4]) = v;
      }
      #pragma unroll
      for (int j = 0; j < 8; j++) {
        int i = threadIdx.x + j * 256;
        int k = i >> 5, cc4 = (i & 31) * 4;
        *reinterpret_cast<float4*>(&Bs[k][cc4]) =
            *reinterpret_cast<const float4*>(&Wsrc[(k0 + k) * HID + cc4]);
      }
      __syncthreads();

      if (ch == 0) {
        float4 bv = *reinterpret_cast<float4*>(&bls[c4]);
        #pragma unroll
        for (int rr = 0; rr < 8; rr++) acc[rr] = bv;
      }
      #pragma unroll 8
      for (int k = 0; k < 64; k++) {
        float4 bv = *reinterpret_cast<float4*>(&Bs[k][c4]);
        #pragma unroll
        for (int rr = 0; rr < 8; rr++) {
          float a = As[rg * 8 + rr][k];
          acc[rr].x += a * bv.x; acc[rr].y += a * bv.y;
          acc[rr].z += a * bv.z; acc[rr].w += a * bv.w;
        }
      }
    }
    #pragma unroll
    for (int rr = 0; rr < 8; rr++) {
      int row = rb + rg * 8 + rr;
      if (row < N)
        *reinterpret_cast<float4*>(&outf[row * HID + c4]) = acc[rr];
    }
  }
}

// ---------------------------------------------------------------------------
// classifier head
// ---------------------------------------------------------------------------
__global__ void k_wn(const float* __restrict__ Wc, float* __restrict__ wn)
{
  int c = threadIdx.x;
  if (c >= NCLS) return;
  float s = 0.f;
  for (int k = 0; k < HID; k++) { float v = Wc[k * NCLS + c]; s += v * v; }
  float scale = 1.f / fmaxf(sqrtf(s), 1e-12f);
  for (int k = 0; k < HID; k++) wn[k * NCLS + c] = Wc[k * NCLS + c] * scale;
}

// one wave per row: lanes hold dims, row-normalize, then lane=class via shfl
__global__ __launch_bounds__(256) void k_classifier(
    const float* __restrict__ outf, const float* __restrict__ wn,
    float* __restrict__ out, int N)
{
  __shared__ float wns[HID * NCLS + 64];   // padded: lanes 50..63 read garbage, never stored
  for (int i = threadIdx.x; i < HID * NCLS / 2; i += 256)
    reinterpret_cast<float2*>(wns)[i] = reinterpret_cast<const float2*>(wn)[i];
  __syncthreads();

  const int lane = threadIdx.x & 63;
  const int gw = (blockIdx.x * 256 + threadIdx.x) >> 6;
  const int nw = (gridDim.x * 256) >> 6;

  for (int r = gw; r < N; r += nw) {
    float of0 = outf[r * HID + lane];
    float of1 = outf[r * HID + 64 + lane];
    float ss = of0 * of0 + of1 * of1;
    #pragma unroll
    for (int off = 32; off >= 1; off >>= 1) ss += __shfl_xor(ss, off);
    float scale = 10.f / fmaxf(sqrtf(ss), 1e-12f);

    float acc = 0.f;
    #pragma unroll 4
    for (int k = 0; k < 64; k++) {
      float a0 = __shfl(of0, k);
      float a1 = __shfl(of1, k);
      acc += a0 * wns[k * NCLS + lane];
      acc += a1 * wns[(k + 64) * NCLS + lane];
    }
    if (lane < NCLS) out[r * NCLS + lane] = scale * acc;
  }
}

// ---------------------------------------------------------------------------
extern "C" void kernel_launch(void* const* d_in, const int* in_sizes, int n_in,
                              void* d_out, int out_size, void* d_ws, size_t ws_size,
                              hipStream_t stream)
{
  const float* x     = (const float*)d_in[0];
  const int*   ei    = (const int*)d_in[1];
  const float* W_in  = (const float*)d_in[2];
  const float* b_in  = (const float*)d_in[3];
  const float* W_l   = (const float*)d_in[4];
  const float* b_l   = (const float*)d_in[5];
  const float* W_r   = (const float*)d_in[6];
  const float* W_cls = (const float*)d_in[7];

  const int N = in_sizes[0] / INDIM;
  const int E = in_sizes[1] / 2;
  const int* src = ei;
  const int* dst = ei + E;

  float* out  = (float*)d_out;
  float* outf = out + (size_t)N * NCLS;   // out_feat output region
  float* feat = outf;                     // encoder output aliases out_feat (see k_combine note)

  char* ws = (char*)d_ws;
  size_t off = 0;
  auto alloc = [&](size_t bytes) -> void* {
    void* p = ws + off;
    off = (off + bytes + 255) & ~(size_t)255;
    return p;
  };
  float* mean = (float*)alloc((size_t)N * HID * 4);
  float* wn   = (float*)alloc((size_t)HID * NCLS * 4);
  int*   cnt  = (int*)alloc((size_t)N * 4);
  int*   rs   = (int*)alloc((size_t)(N + 1) * 4);
  int*   cur  = (int*)alloc((size_t)N * 4);
  int*   csr  = (int*)alloc((size_t)E * 4);
  int*   part = (int*)alloc((size_t)SNB * 4);
  (void)ws_size; (void)n_in; (void)out_size;

  hipMemsetAsync(cnt, 0, (size_t)N * 4, stream);
  k_wn<<<1, 64, 0, stream>>>(W_cls, wn);
  k_encoder<<<(N + 63) / 64, 256, 0, stream>>>(x, W_in, b_in, feat, N);
  k_count<<<(E + 255) / 256, 256, 0, stream>>>(dst, cnt, E);
  k_scan_a<<<SNB, SBS, 0, stream>>>(cnt, part, N);
  k_scan_b<<<1, SNB, 0, stream>>>(part);
  k_scan_c<<<SNB, SBS, 0, stream>>>(cnt, part, rs, cur, N, E);
  k_fill<<<(E + 255) / 256, 256, 0, stream>>>(src, dst, cur, csr, E);
  k_agg<<<4096, 256, 0, stream>>>(feat, rs, csr, mean, N);
  k_combine<<<(N + 63) / 64, 256, 0, stream>>>(mean, feat, W_l, W_r, b_l, outf, N);
  k_classifier<<<2048, 256, 0, stream>>>(outf, wn, out, N);
}